// Round 3
// baseline (17965.765 us; speedup 1.0000x reference)
//
#include <hip/hip_runtime.h>
#include <stdint.h>

// ============================================================================
// RNN2Layer: proj GEMM -> persistent Euler-scan kernel -> output GEMM
// All fp32. Round 3: round-2 scan was LDS-pipe + exposed-latency bound at
// 1 wave/SIMD (VALUBusy 15.7%, bank conflicts 4.8e8). Changes:
//  - 512 threads/WG (8 waves = 2/SIMD -> TLP hides LDS/LLC latency)
//  - fused weights (B+C) held in 64 VGPRs/thread -> NO weight LDS at all
//  - LDS = h staging only (2 phase bufs x 8 rows x 512), involution swizzle
//    perm(slot)=slot^((slot>>3)&7) on both write and read: every 8-lane
//    batch hits 8 distinct bank quads -> conflict-free by construction
//  - ReLU folded into main loop via km-select (chunks are block-aligned);
//    no correction pass, no divergent hot spot
//  - 2 barriers/step; flag publish = per-wave s_waitcnt vmcnt(0) +
//    system-scope fetch_add (count 8/step) -> no end-of-step barrier
//  - 64KB LDS pad forces exactly 1 WG/CU for the persistent launch
// Cross-WG protocol unchanged: system-scope relaxed atomics (sc0 sc1,
// coherent at LLC), zero cache maintenance on the critical path.
//
// Layout of d_out:  [0 .. 16777216)                 output     [1024][64][256]
//                   [16777216 .. 16777216+67108864) embeddings [1024][64][1024]
// emb initially holds proj (= input @ W_in); scan overwrites emb[t] with h_t
// after consuming u_t = proj[t] (same thread -> no hazard).
// d_ws: 256 u32 flags (memset 0 on stream).
// ============================================================================

#define T_STEPS 1024
#define HDIM    1024
#define EUL     0.01f

typedef unsigned long long u64_t;

// Coherent (L1+L2-bypassing) 16B load as 2x 8B system-scope relaxed atomics.
__device__ __forceinline__ float4 ldg_sys16(const float* p) {
  union { u64_t u; float f[2]; } a, b;
  a.u = __hip_atomic_load((const u64_t*)p,       __ATOMIC_RELAXED,
                          __HIP_MEMORY_SCOPE_SYSTEM);
  b.u = __hip_atomic_load((const u64_t*)(p + 2), __ATOMIC_RELAXED,
                          __HIP_MEMORY_SCOPE_SYSTEM);
  float4 r;
  r.x = a.f[0]; r.y = a.f[1]; r.z = b.f[0]; r.w = b.f[1];
  return r;
}

__device__ __forceinline__ void fma4(float4& a, float s, const float4& v) {
  a.x += s * v.x; a.y += s * v.y; a.z += s * v.z; a.w += s * v.w;
}

// ---------------------------------------------------------------------------
// Generic fp32 GEMM: C[M,N] = A[M,K] @ B[K,N], row-major, M%64==N%64==K%16==0
// 64x64 tile, 256 threads, 4x4 microtile.  (unchanged)
// ---------------------------------------------------------------------------
__global__ __launch_bounds__(256) void gemm_f32(const float* __restrict__ A,
                                                const float* __restrict__ B,
                                                float* __restrict__ C,
                                                int M, int N, int K) {
  __shared__ float As[16][68];
  __shared__ float Bs[16][68];
  const int tid = threadIdx.x;
  const int tx = tid & 15;
  const int ty = tid >> 4;
  const int m0 = blockIdx.y * 64;
  const int n0 = blockIdx.x * 64;
  float acc[4][4] = {};

  for (int k0 = 0; k0 < K; k0 += 16) {
    {
      const int m = tid >> 2;
      const int k = (tid & 3) * 4;
      const float4 a = *(const float4*)(A + (long)(m0 + m) * K + k0 + k);
      As[k + 0][m] = a.x; As[k + 1][m] = a.y;
      As[k + 2][m] = a.z; As[k + 3][m] = a.w;
      const int kb = tid >> 4;
      const int n  = (tid & 15) * 4;
      *(float4*)&Bs[kb][n] = *(const float4*)(B + (long)(k0 + kb) * N + n0 + n);
    }
    __syncthreads();
#pragma unroll
    for (int k = 0; k < 16; ++k) {
      const float4 a = *(const float4*)&As[k][ty * 4];
      const float4 b = *(const float4*)&Bs[k][tx * 4];
      acc[0][0] += a.x * b.x; acc[0][1] += a.x * b.y; acc[0][2] += a.x * b.z; acc[0][3] += a.x * b.w;
      acc[1][0] += a.y * b.x; acc[1][1] += a.y * b.y; acc[1][2] += a.y * b.z; acc[1][3] += a.y * b.w;
      acc[2][0] += a.z * b.x; acc[2][1] += a.z * b.y; acc[2][2] += a.z * b.z; acc[2][3] += a.z * b.w;
      acc[3][0] += a.w * b.x; acc[3][1] += a.w * b.y; acc[3][2] += a.w * b.z; acc[3][3] += a.w * b.w;
    }
    __syncthreads();
  }
#pragma unroll
  for (int i = 0; i < 4; ++i) {
    float4 o;
    o.x = acc[i][0]; o.y = acc[i][1]; o.z = acc[i][2]; o.w = acc[i][3];
    *(float4*)(C + (long)(m0 + ty * 4 + i) * N + n0 + tx * 4) = o;
  }
}

// ---------------------------------------------------------------------------
// Persistent scan kernel, 512 threads.
// Grid: 256 WGs = 8 batch-groups (g = w&7, rows 8g..8g+8) x 32 col slices
// (c = w>>3, cols 32c..32c+32).
// Thread: qd = tid>>6 (wave, j-quad: cols cb+4qd..+4; also staging row qd),
//         l  = tid&63 (i-split: phase-p rows p*512 + 8l .. +8;
//                      staging cols ph0 [8l,8l+8), ph1 [512+8l, +8)).
// Weights: Creg[p*8+r] = (B+C)[p*512+8l+r][cb+4qd..+4] in VGPRs.
// LDS: hls[2][8][512] staged prev h, swizzled by perm(slot)=slot^((slot>>3)&7)
//      at 16B-slot granularity (slot = phase-local float idx / 4).
// Reduce: shfl_xor reduce-scatter; lane ends with output (b_f,j_f),
//         b_f=(l&31)>>2, j_f=4qd+(l&3); lanes<32 store.
// Publish: per-wave vmcnt(0) drain + system fetch_add(flags[w],1) => 8/step.
// ---------------------------------------------------------------------------
__global__ __launch_bounds__(512) void scan_kernel(
    const float* __restrict__ block_mat,
    const float* __restrict__ coupling_mat,
    float* __restrict__ emb,          // [T][64][1024]; holds proj on entry
    unsigned int* __restrict__ flags) // [256], zeroed before launch
{
  __shared__ float hls[2][8 * 512];   // 32 KB staged h (2 phase buffers)
  __shared__ float lds_pad[16384];    // 64 KB pad: total 96KB -> 1 WG/CU

  const int tid = threadIdx.x;
  lds_pad[0] = 0.f;  // keep pad allocated (forces occupancy), trivial cost

  const int w = blockIdx.x;
  const int g = w & 7;            // batch group -> rows [8g, 8g+8)
  const int c = w >> 3;           // col slice   -> cols [32c, 32c+32)
  const int b0 = g * 8;
  const int cb = c * 32;
  const int bk = c >> 1;          // 64-wide diag block index (WG-uniform)
  const int blk_phase = bk >> 3;  // phase containing own-block rows
  const int qd = tid >> 6;        // wave id = j-quad = staging row
  const int l  = tid & 63;        // lane = i-split = staging col chunk
  const int lf = l & 31;
  const int b_f = lf >> 2;                // output batch row 0..7
  const int j_f = (qd << 2) | (lf & 3);   // output col within slice

  // in-block: thread's chunk rows (phase-local 8l..8l+8) inside diag block?
  const bool in_blk = ((l >> 3) == (bk & 7));
  const float km = in_blk ? 0.f : 1.f;    // fmaxf(h, h*km): relu iff in_blk

  // swizzled 16B-slot indices (same for staging write and compute read)
  const int s0 = 2 * l, s1 = 2 * l + 1;
  const int rs0 = s0 ^ ((s0 >> 3) & 7);
  const int rs1 = s1 ^ ((s1 >> 3) & 7);

  // h_old address (own previous-state element)
  const int gcol = cb + j_f;
  const int hop = gcol >> 9;              // phase buf holding own col
  const int il = gcol & 511;
  const int hslot = il >> 2;
  const int hperm = hslot ^ ((hslot >> 3) & 7);
  const int hoff = b_f * 512 + (hperm << 2) + (il & 3);

  // ---- fused weight slice into registers: 16 rows x 4 cols
  float4 Creg[16];
#pragma unroll
  for (int p = 0; p < 2; ++p) {
#pragma unroll
    for (int r = 0; r < 8; ++r) {
      const long i = (long)(p * 512 + l * 8 + r);
      const float4 bv = *(const float4*)(block_mat    + i * HDIM + cb + (qd << 2));
      const float4 cv = *(const float4*)(coupling_mat + i * HDIM + cb + (qd << 2));
      float4 rr;
      rr.x = bv.x + cv.x; rr.y = bv.y + cv.y;
      rr.z = bv.z + cv.z; rr.w = bv.w + cv.w;
      Creg[p * 8 + r] = rr;
    }
  }

  // flags this thread polls (producers of its staged col chunks)
  const int f0 = ((l >> 2) << 3) | g;   // phase-0 producer WG id
  const int f1 = f0 + 128;              // phase-1 producer WG id

  long spin_budget = 20000000;  // lifetime poll budget: hang-safety valve

// one phase of the dense matvec: 16 ds_read_b128 + 64 fma4 (+ relu select)
#define PHASE_MAC(P)                                                        \
  {                                                                         \
    const bool do_relu = ((P) == blk_phase);                                \
    _Pragma("unroll")                                                       \
    for (int b = 0; b < 8; ++b) {                                           \
      const float* Hb = &hls[(P)][b * 512];                                 \
      float4 h0 = *(const float4*)(Hb + (rs0 << 2));                        \
      float4 h1 = *(const float4*)(Hb + (rs1 << 2));                        \
      if (do_relu) {                                                        \
        h0.x = fmaxf(h0.x, h0.x * km); h0.y = fmaxf(h0.y, h0.y * km);       \
        h0.z = fmaxf(h0.z, h0.z * km); h0.w = fmaxf(h0.w, h0.w * km);       \
        h1.x = fmaxf(h1.x, h1.x * km); h1.y = fmaxf(h1.y, h1.y * km);       \
        h1.z = fmaxf(h1.z, h1.z * km); h1.w = fmaxf(h1.w, h1.w * km);       \
      }                                                                     \
      fma4(acc[b], h0.x, Creg[(P) * 8 + 0]);                                \
      fma4(acc[b], h0.y, Creg[(P) * 8 + 1]);                                \
      fma4(acc[b], h0.z, Creg[(P) * 8 + 2]);                                \
      fma4(acc[b], h0.w, Creg[(P) * 8 + 3]);                                \
      fma4(acc[b], h1.x, Creg[(P) * 8 + 4]);                                \
      fma4(acc[b], h1.y, Creg[(P) * 8 + 5]);                                \
      fma4(acc[b], h1.z, Creg[(P) * 8 + 6]);                                \
      fma4(acc[b], h1.w, Creg[(P) * 8 + 7]);                                \
    }                                                                       \
  }

  for (int t = 0; t < T_STEPS; ++t) {
    float4 acc[8];
#pragma unroll
    for (int b = 0; b < 8; ++b) { acc[b].x = 0.f; acc[b].y = 0.f; acc[b].z = 0.f; acc[b].w = 0.f; }
    float h_old = 0.f;

    // u_t = proj[t] for our output element (plain cached load; only we touch
    // this element, and we read before our own overwrite)
    const float u = emb[((long)t * 64 + b0 + b_f) * HDIM + cb + j_f];

    if (t > 0) {
      const unsigned int tgt = (unsigned int)(8 * t);  // 8 wave-incs per step

      // ---- poll phase-0 producer, then issue phase-0 staged loads
      while (__hip_atomic_load(&flags[f0], __ATOMIC_RELAXED,
                               __HIP_MEMORY_SCOPE_SYSTEM) < tgt) {
        __builtin_amdgcn_s_sleep(1);
        if (--spin_budget < 0) break;
      }
      asm volatile("" ::: "memory");
      const float* src0 =
          emb + ((long)(t - 1) * 64 + b0 + qd) * HDIM + (l << 3);
      const float4 stg0a = ldg_sys16(src0);
      const float4 stg0b = ldg_sys16(src0 + 4);

      // ---- poll phase-1 producer, issue phase-1 staged loads
      while (__hip_atomic_load(&flags[f1], __ATOMIC_RELAXED,
                               __HIP_MEMORY_SCOPE_SYSTEM) < tgt) {
        __builtin_amdgcn_s_sleep(1);
        if (--spin_budget < 0) break;
      }
      asm volatile("" ::: "memory");
      const float4 stg1a = ldg_sys16(src0 + 512);
      const float4 stg1b = ldg_sys16(src0 + 516);

      // ---- write phase 0 (row qd, swizzled slots 2l, 2l+1)
      *(float4*)&hls[0][qd * 512 + (rs0 << 2)] = stg0a;
      *(float4*)&hls[0][qd * 512 + (rs1 << 2)] = stg0b;
      __syncthreads();  // bar_a: phase-0 staged & visible

      if (hop == 0) h_old = hls[0][hoff];  // safe: hls[0] stable until bar_b
      PHASE_MAC(0)

      // ---- write phase 1 (disjoint buffer; phase-1 load latency was hidden
      //      under phase-0 compute)
      *(float4*)&hls[1][qd * 512 + (rs0 << 2)] = stg1a;
      *(float4*)&hls[1][qd * 512 + (rs1 << 2)] = stg1b;
      __syncthreads();  // bar_b: phase-1 staged; also gates next-step write0

      if (hop == 1) h_old = hls[1][hoff];  // safe: hls[1] stable until bar_a(t+1)
      PHASE_MAC(1)
    }

    // ---- reduce-scatter 64-way i-split over the wave (shfl only).
    // 5 rounds within each 32-lane half, then cross-half merge; lane ends
    // with output idx (l&31): b_f = (l&31)>>2, j_f col (l&3).
    float red[32];
#pragma unroll
    for (int b = 0; b < 8; ++b) {
      red[b * 4 + 0] = acc[b].x;
      red[b * 4 + 1] = acc[b].y;
      red[b * 4 + 2] = acc[b].z;
      red[b * 4 + 3] = acc[b].w;
    }
#define RED_ROUND(M)                                              \
    {                                                             \
      const bool hi = (tid & (M)) != 0;                           \
      _Pragma("unroll")                                           \
      for (int q = 0; q < (M); ++q) {                             \
        const float lo = red[q], hv2 = red[q + (M)];              \
        const float keep = hi ? hv2 : lo;                         \
        const float give = hi ? lo : hv2;                         \
        red[q] = keep + __shfl_xor(give, (M), 64);                \
      }                                                           \
    }
    RED_ROUND(16)
    RED_ROUND(8)
    RED_ROUND(4)
    RED_ROUND(2)
    RED_ROUND(1)
#undef RED_ROUND
    const float tot = red[0] + __shfl_xor(red[0], 32, 64);

    // ---- Euler update + publish (store bypasses L1/L2 -> visible at LLC)
    const float hn = h_old + EUL * (-h_old + tot + u);
    if (lf == l) {  // lanes 0..31 hold the canonical copy
      __hip_atomic_store(&emb[((long)t * 64 + b0 + b_f) * HDIM + cb + j_f], hn,
                         __ATOMIC_RELAXED, __HIP_MEMORY_SCOPE_SYSTEM);
    }
    // per-wave publish: wait own wave's stores complete at LLC, then count.
    asm volatile("s_waitcnt vmcnt(0)" ::: "memory");
    if (l == 0) {
      (void)__hip_atomic_fetch_add(&flags[w], 1u, __ATOMIC_RELAXED,
                                   __HIP_MEMORY_SCOPE_SYSTEM);
    }
  }
#undef PHASE_MAC
}

// ---------------------------------------------------------------------------
extern "C" void kernel_launch(void* const* d_in, const int* in_sizes, int n_in,
                              void* d_out, int out_size, void* d_ws,
                              size_t ws_size, hipStream_t stream) {
  (void)in_sizes; (void)n_in; (void)out_size; (void)ws_size;
  const float* input     = (const float*)d_in[0];  // [1024*64, 256]
  const float* input_mat = (const float*)d_in[1];  // [256, 1024]
  const float* block_mat = (const float*)d_in[2];  // [1024, 1024]
  const float* coupling  = (const float*)d_in[3];  // [1024, 1024]
  const float* out_mat   = (const float*)d_in[4];  // [1024, 256]

  float* out_ptr = (float*)d_out;                       // [65536, 256]
  float* emb_ptr = out_ptr + (size_t)1024 * 64 * 256;   // [65536, 1024]
  unsigned int* flags = (unsigned int*)d_ws;

  // 1) proj = input @ input_mat  -> embeddings region (consumed in-place)
  gemm_f32<<<dim3(1024 / 64, 65536 / 64), 256, 0, stream>>>(
      input, input_mat, emb_ptr, 65536, 1024, 256);

  // 2) zero the step flags
  hipMemsetAsync(flags, 0, 256 * sizeof(unsigned int), stream);

  // 3) persistent scan (256 WGs x 512 threads, 1/CU by LDS footprint)
  scan_kernel<<<256, 512, 0, stream>>>(block_mat, coupling, emb_ptr, flags);

  // 4) output = embeddings @ out_mat
  gemm_f32<<<dim3(256 / 64, 65536 / 64), 256, 0, stream>>>(
      emb_ptr, out_mat, out_ptr, 65536, 256, 1024);
}

// Round 4
// 17336.462 us; speedup vs baseline: 1.0363x; 1.0363x over previous
//
#include <hip/hip_runtime.h>
#include <stdint.h>

// ============================================================================
// RNN2Layer: proj GEMM -> persistent Euler-scan kernel -> output GEMM
// All fp32. Round 4: round 3's design (reg-resident weights, 8 waves/WG)
// regressed because (a) the compiler targeted 112 VGPRs (no launch_bounds
// occupancy arg) and SPILLED ~40 regs to scratch (+370 MB HBM traffic,
// exposed ~900cy reloads at 2 waves/SIMD), and (b) the LDS occupancy pad
// was dead-store-eliminated. Fixes:
//  - __launch_bounds__(512, 2): VGPR cap 256 (2 waves/SIMD = exactly the
//    1-WG/CU residency the grid gives); working set ~145 VGPR -> no spill
//  - volatile write to the pad -> 96 KB LDS pins 1 WG/CU for real
//  - u-load only on lanes 0..31 (lanes 32..63 never used it)
// Everything else as round 3: weights fused (B+C) in 64 VGPRs/thread, LDS
// only stages prev-h (2 x 8 x 512, involution-swizzled, conflict-free to
// the b128 minimum), ReLU folded via km-select, shfl reduce-scatter,
// per-wave vmcnt(0)+fetch_add publish (8/step), per-thread producer polls.
// Cross-WG protocol: system-scope relaxed atomics (sc0 sc1, LLC-coherent),
// zero cache maintenance on the critical path.
//
// Layout of d_out:  [0 .. 16777216)                 output     [1024][64][256]
//                   [16777216 .. 16777216+67108864) embeddings [1024][64][1024]
// emb initially holds proj (= input @ W_in); scan overwrites emb[t] with h_t
// after consuming u_t = proj[t] (same thread -> no hazard).
// d_ws: 256 u32 flags (memset 0 on stream).
// ============================================================================

#define T_STEPS 1024
#define HDIM    1024
#define EUL     0.01f

typedef unsigned long long u64_t;

// Coherent (L1+L2-bypassing) 16B load as 2x 8B system-scope relaxed atomics.
__device__ __forceinline__ float4 ldg_sys16(const float* p) {
  union { u64_t u; float f[2]; } a, b;
  a.u = __hip_atomic_load((const u64_t*)p,       __ATOMIC_RELAXED,
                          __HIP_MEMORY_SCOPE_SYSTEM);
  b.u = __hip_atomic_load((const u64_t*)(p + 2), __ATOMIC_RELAXED,
                          __HIP_MEMORY_SCOPE_SYSTEM);
  float4 r;
  r.x = a.f[0]; r.y = a.f[1]; r.z = b.f[0]; r.w = b.f[1];
  return r;
}

__device__ __forceinline__ void fma4(float4& a, float s, const float4& v) {
  a.x += s * v.x; a.y += s * v.y; a.z += s * v.z; a.w += s * v.w;
}

// ---------------------------------------------------------------------------
// Generic fp32 GEMM: C[M,N] = A[M,K] @ B[K,N], row-major, M%64==N%64==K%16==0
// 64x64 tile, 256 threads, 4x4 microtile.  (unchanged)
// ---------------------------------------------------------------------------
__global__ __launch_bounds__(256) void gemm_f32(const float* __restrict__ A,
                                                const float* __restrict__ B,
                                                float* __restrict__ C,
                                                int M, int N, int K) {
  __shared__ float As[16][68];
  __shared__ float Bs[16][68];
  const int tid = threadIdx.x;
  const int tx = tid & 15;
  const int ty = tid >> 4;
  const int m0 = blockIdx.y * 64;
  const int n0 = blockIdx.x * 64;
  float acc[4][4] = {};

  for (int k0 = 0; k0 < K; k0 += 16) {
    {
      const int m = tid >> 2;
      const int k = (tid & 3) * 4;
      const float4 a = *(const float4*)(A + (long)(m0 + m) * K + k0 + k);
      As[k + 0][m] = a.x; As[k + 1][m] = a.y;
      As[k + 2][m] = a.z; As[k + 3][m] = a.w;
      const int kb = tid >> 4;
      const int n  = (tid & 15) * 4;
      *(float4*)&Bs[kb][n] = *(const float4*)(B + (long)(k0 + kb) * N + n0 + n);
    }
    __syncthreads();
#pragma unroll
    for (int k = 0; k < 16; ++k) {
      const float4 a = *(const float4*)&As[k][ty * 4];
      const float4 b = *(const float4*)&Bs[k][tx * 4];
      acc[0][0] += a.x * b.x; acc[0][1] += a.x * b.y; acc[0][2] += a.x * b.z; acc[0][3] += a.x * b.w;
      acc[1][0] += a.y * b.x; acc[1][1] += a.y * b.y; acc[1][2] += a.y * b.z; acc[1][3] += a.y * b.w;
      acc[2][0] += a.z * b.x; acc[2][1] += a.z * b.y; acc[2][2] += a.z * b.z; acc[2][3] += a.z * b.w;
      acc[3][0] += a.w * b.x; acc[3][1] += a.w * b.y; acc[3][2] += a.w * b.z; acc[3][3] += a.w * b.w;
    }
    __syncthreads();
  }
#pragma unroll
  for (int i = 0; i < 4; ++i) {
    float4 o;
    o.x = acc[i][0]; o.y = acc[i][1]; o.z = acc[i][2]; o.w = acc[i][3];
    *(float4*)(C + (long)(m0 + ty * 4 + i) * N + n0 + tx * 4) = o;
  }
}

// ---------------------------------------------------------------------------
// Persistent scan kernel, 512 threads.
// Grid: 256 WGs = 8 batch-groups (g = w&7, rows 8g..8g+8) x 32 col slices
// (c = w>>3, cols 32c..32c+32).
// Thread: qd = tid>>6 (wave, j-quad: cols cb+4qd..+4; also staging row qd),
//         l  = tid&63 (i-split: phase-p rows p*512 + 8l .. +8;
//                      staging cols ph0 [8l,8l+8), ph1 [512+8l, +8)).
// Weights: Creg[p*8+r] = (B+C)[p*512+8l+r][cb+4qd..+4] in VGPRs (64 regs).
// LDS: hls[2][8][512] staged prev h, swizzled by perm(slot)=slot^((slot>>3)&7)
//      at 16B-slot granularity; conflict-free to the wave64-b128 minimum.
// Reduce: shfl_xor reduce-scatter; lane ends with output (b_f,j_f),
//         b_f=(l&31)>>2, j_f=4qd+(l&3); lanes 0..31 store.
// Publish: per-wave vmcnt(0) drain + system fetch_add(flags[w],1) => 8/step.
// ---------------------------------------------------------------------------
__global__ __launch_bounds__(512, 2) void scan_kernel(
    const float* __restrict__ block_mat,
    const float* __restrict__ coupling_mat,
    float* __restrict__ emb,          // [T][64][1024]; holds proj on entry
    unsigned int* __restrict__ flags) // [256], zeroed before launch
{
  __shared__ float hls[2][8 * 512];   // 32 KB staged h (2 phase buffers)
  __shared__ float lds_pad[16384];    // 64 KB pad: total 96KB -> 1 WG/CU

  const int tid = threadIdx.x;
  // volatile so the pad cannot be dead-store-eliminated (round-3 bug:
  // LDS_Block_Size showed 32768 -> pad was gone, occupancy unpinned)
  *(volatile float*)&lds_pad[tid] = 0.f;

  const int w = blockIdx.x;
  const int g = w & 7;            // batch group -> rows [8g, 8g+8)
  const int c = w >> 3;           // col slice   -> cols [32c, 32c+32)
  const int b0 = g * 8;
  const int cb = c * 32;
  const int bk = c >> 1;          // 64-wide diag block index (WG-uniform)
  const int blk_phase = bk >> 3;  // phase containing own-block rows
  const int qd = tid >> 6;        // wave id = j-quad = staging row
  const int l  = tid & 63;        // lane = i-split = staging col chunk
  const int lf = l & 31;
  const int b_f = lf >> 2;                // output batch row 0..7
  const int j_f = (qd << 2) | (lf & 3);   // output col within slice

  // in-block: thread's chunk rows (phase-local 8l..8l+8) inside diag block?
  const bool in_blk = ((l >> 3) == (bk & 7));
  const float km = in_blk ? 0.f : 1.f;    // fmaxf(h, h*km): relu iff in_blk

  // swizzled 16B-slot indices (same for staging write and compute read)
  const int s0 = 2 * l, s1 = 2 * l + 1;
  const int rs0 = s0 ^ ((s0 >> 3) & 7);
  const int rs1 = s1 ^ ((s1 >> 3) & 7);

  // h_old address (own previous-state element)
  const int gcol = cb + j_f;
  const int hop = gcol >> 9;              // phase buf holding own col
  const int il = gcol & 511;
  const int hslot = il >> 2;
  const int hperm = hslot ^ ((hslot >> 3) & 7);
  const int hoff = b_f * 512 + (hperm << 2) + (il & 3);

  // ---- fused weight slice into registers: 16 rows x 4 cols (64 VGPRs)
  float4 Creg[16];
#pragma unroll
  for (int p = 0; p < 2; ++p) {
#pragma unroll
    for (int r = 0; r < 8; ++r) {
      const long i = (long)(p * 512 + l * 8 + r);
      const float4 bv = *(const float4*)(block_mat    + i * HDIM + cb + (qd << 2));
      const float4 cv = *(const float4*)(coupling_mat + i * HDIM + cb + (qd << 2));
      float4 rr;
      rr.x = bv.x + cv.x; rr.y = bv.y + cv.y;
      rr.z = bv.z + cv.z; rr.w = bv.w + cv.w;
      Creg[p * 8 + r] = rr;
    }
  }

  // flags this thread polls (producers of its staged col chunks)
  const int f0 = ((l >> 2) << 3) | g;   // phase-0 producer WG id
  const int f1 = f0 + 128;              // phase-1 producer WG id

  long spin_budget = 20000000;  // lifetime poll budget: hang-safety valve

// one phase of the dense matvec: 16 ds_read_b128 + 64 fma4 (+ relu select)
#define PHASE_MAC(P)                                                        \
  {                                                                         \
    const bool do_relu = ((P) == blk_phase);                                \
    _Pragma("unroll")                                                       \
    for (int b = 0; b < 8; ++b) {                                           \
      const float* Hb = &hls[(P)][b * 512];                                 \
      float4 h0 = *(const float4*)(Hb + (rs0 << 2));                        \
      float4 h1 = *(const float4*)(Hb + (rs1 << 2));                        \
      if (do_relu) {                                                        \
        h0.x = fmaxf(h0.x, h0.x * km); h0.y = fmaxf(h0.y, h0.y * km);       \
        h0.z = fmaxf(h0.z, h0.z * km); h0.w = fmaxf(h0.w, h0.w * km);       \
        h1.x = fmaxf(h1.x, h1.x * km); h1.y = fmaxf(h1.y, h1.y * km);       \
        h1.z = fmaxf(h1.z, h1.z * km); h1.w = fmaxf(h1.w, h1.w * km);       \
      }                                                                     \
      fma4(acc[b], h0.x, Creg[(P) * 8 + 0]);                                \
      fma4(acc[b], h0.y, Creg[(P) * 8 + 1]);                                \
      fma4(acc[b], h0.z, Creg[(P) * 8 + 2]);                                \
      fma4(acc[b], h0.w, Creg[(P) * 8 + 3]);                                \
      fma4(acc[b], h1.x, Creg[(P) * 8 + 4]);                                \
      fma4(acc[b], h1.y, Creg[(P) * 8 + 5]);                                \
      fma4(acc[b], h1.z, Creg[(P) * 8 + 6]);                                \
      fma4(acc[b], h1.w, Creg[(P) * 8 + 7]);                                \
    }                                                                       \
  }

  for (int t = 0; t < T_STEPS; ++t) {
    float4 acc[8];
#pragma unroll
    for (int b = 0; b < 8; ++b) { acc[b].x = 0.f; acc[b].y = 0.f; acc[b].z = 0.f; acc[b].w = 0.f; }
    float h_old = 0.f;

    // u_t = proj[t] for our output element; only lanes 0..31 produce output
    float u = 0.f;
    if (l < 32) u = emb[((long)t * 64 + b0 + b_f) * HDIM + cb + j_f];

    if (t > 0) {
      const unsigned int tgt = (unsigned int)(8 * t);  // 8 wave-incs per step

      // ---- poll phase-0 producer, then issue phase-0 staged loads
      while (__hip_atomic_load(&flags[f0], __ATOMIC_RELAXED,
                               __HIP_MEMORY_SCOPE_SYSTEM) < tgt) {
        __builtin_amdgcn_s_sleep(1);
        if (--spin_budget < 0) break;
      }
      asm volatile("" ::: "memory");
      const float* src0 =
          emb + ((long)(t - 1) * 64 + b0 + qd) * HDIM + (l << 3);
      const float4 stg0a = ldg_sys16(src0);
      const float4 stg0b = ldg_sys16(src0 + 4);

      // ---- poll phase-1 producer, issue phase-1 staged loads
      while (__hip_atomic_load(&flags[f1], __ATOMIC_RELAXED,
                               __HIP_MEMORY_SCOPE_SYSTEM) < tgt) {
        __builtin_amdgcn_s_sleep(1);
        if (--spin_budget < 0) break;
      }
      asm volatile("" ::: "memory");
      const float4 stg1a = ldg_sys16(src0 + 512);
      const float4 stg1b = ldg_sys16(src0 + 516);

      // ---- write phase 0 (row qd, swizzled slots 2l, 2l+1)
      *(float4*)&hls[0][qd * 512 + (rs0 << 2)] = stg0a;
      *(float4*)&hls[0][qd * 512 + (rs1 << 2)] = stg0b;
      __syncthreads();  // bar_a: phase-0 staged & visible

      if (hop == 0) h_old = hls[0][hoff];  // safe: hls[0] stable until bar_b
      PHASE_MAC(0)

      // ---- write phase 1 (disjoint buffer; phase-1 load latency was hidden
      //      under phase-0 compute)
      *(float4*)&hls[1][qd * 512 + (rs0 << 2)] = stg1a;
      *(float4*)&hls[1][qd * 512 + (rs1 << 2)] = stg1b;
      __syncthreads();  // bar_b: phase-1 staged; also gates next-step write0

      if (hop == 1) h_old = hls[1][hoff];  // safe: hls[1] stable until bar_a(t+1)
      PHASE_MAC(1)
    }

    // ---- reduce-scatter 64-way i-split over the wave (shfl only).
    // 5 rounds within each 32-lane half, then cross-half merge; lane ends
    // with output idx (l&31): b_f = (l&31)>>2, j_f col (l&3).
    float red[32];
#pragma unroll
    for (int b = 0; b < 8; ++b) {
      red[b * 4 + 0] = acc[b].x;
      red[b * 4 + 1] = acc[b].y;
      red[b * 4 + 2] = acc[b].z;
      red[b * 4 + 3] = acc[b].w;
    }
#define RED_ROUND(M)                                              \
    {                                                             \
      const bool hi = (l & (M)) != 0;                             \
      _Pragma("unroll")                                           \
      for (int q = 0; q < (M); ++q) {                             \
        const float lo = red[q], hv2 = red[q + (M)];              \
        const float keep = hi ? hv2 : lo;                         \
        const float give = hi ? lo : hv2;                         \
        red[q] = keep + __shfl_xor(give, (M), 64);                \
      }                                                           \
    }
    RED_ROUND(16)
    RED_ROUND(8)
    RED_ROUND(4)
    RED_ROUND(2)
    RED_ROUND(1)
#undef RED_ROUND
    const float tot = red[0] + __shfl_xor(red[0], 32, 64);

    // ---- Euler update + publish (store bypasses L1/L2 -> visible at LLC)
    const float hn = h_old + EUL * (-h_old + tot + u);
    if (l < 32) {  // lanes 0..31 hold the canonical copy
      __hip_atomic_store(&emb[((long)t * 64 + b0 + b_f) * HDIM + cb + j_f], hn,
                         __ATOMIC_RELAXED, __HIP_MEMORY_SCOPE_SYSTEM);
    }
    // per-wave publish: wait own wave's stores complete at LLC, then count.
    asm volatile("s_waitcnt vmcnt(0)" ::: "memory");
    if (l == 0) {
      (void)__hip_atomic_fetch_add(&flags[w], 1u, __ATOMIC_RELAXED,
                                   __HIP_MEMORY_SCOPE_SYSTEM);
    }
  }
#undef PHASE_MAC
}

// ---------------------------------------------------------------------------
extern "C" void kernel_launch(void* const* d_in, const int* in_sizes, int n_in,
                              void* d_out, int out_size, void* d_ws,
                              size_t ws_size, hipStream_t stream) {
  (void)in_sizes; (void)n_in; (void)out_size; (void)ws_size;
  const float* input     = (const float*)d_in[0];  // [1024*64, 256]
  const float* input_mat = (const float*)d_in[1];  // [256, 1024]
  const float* block_mat = (const float*)d_in[2];  // [1024, 1024]
  const float* coupling  = (const float*)d_in[3];  // [1024, 1024]
  const float* out_mat   = (const float*)d_in[4];  // [1024, 256]

  float* out_ptr = (float*)d_out;                       // [65536, 256]
  float* emb_ptr = out_ptr + (size_t)1024 * 64 * 256;   // [65536, 1024]
  unsigned int* flags = (unsigned int*)d_ws;

  // 1) proj = input @ input_mat  -> embeddings region (consumed in-place)
  gemm_f32<<<dim3(1024 / 64, 65536 / 64), 256, 0, stream>>>(
      input, input_mat, emb_ptr, 65536, 1024, 256);

  // 2) zero the step flags
  hipMemsetAsync(flags, 0, 256 * sizeof(unsigned int), stream);

  // 3) persistent scan (256 WGs x 512 threads, 1/CU by LDS footprint)
  scan_kernel<<<256, 512, 0, stream>>>(block_mat, coupling, emb_ptr, flags);

  // 4) output = embeddings @ out_mat
  gemm_f32<<<dim3(256 / 64, 65536 / 64), 256, 0, stream>>>(
      emb_ptr, out_mat, out_ptr, 65536, 256, 1024);
}

// Round 5
// 7386.994 us; speedup vs baseline: 2.4321x; 2.3469x over previous
//
#include <hip/hip_runtime.h>
#include <stdint.h>

// ============================================================================
// RNN2Layer: proj GEMM -> persistent Euler-scan kernel -> output GEMM
// All fp32. Round 5: R4 (512thr, reg-weights, clean LDS) SHOULD beat R2 on
// every pipe yet is 1.8x slower. Spill theory refuted (VGPR 108 fits, R4
// launch_bounds changed nothing). Remaining mechanism: FLAG-LINE CONTENTION
// at the LLC -- 256 flags in 16 cachelines, 131K threads system-scope-polling
// them continuously + 2M fetch_add RMWs (8/WG/step) on the same lines; the
// producer's flag update queues behind the poll storm -> handoff latency
// balloons. This round is a clean A/B on that theory:
//  - flags padded to 1 per 64B line (flags[w*16], 16 KB workspace)
//  - publish = ONE plain relaxed system store per WG per step (after
//    per-wave vmcnt(0) + __syncthreads), not 8 fetch_adds; tgt = t
//  - single merged poll loop (both flags each iteration, as R2 proved),
//    s_sleep(4) to cut poll transaction pressure ~3x
// Everything else identical to R4: reg-resident fused weights (64 VGPR),
// conflict-free involution-swizzled h staging in LDS, intra-wave
// reduce-scatter, system-scope sc0sc1 h exchange, zero cache maintenance.
//
// Layout of d_out:  [0 .. 16777216)                 output     [1024][64][256]
//                   [16777216 .. 16777216+67108864) embeddings [1024][64][1024]
// emb initially holds proj (= input @ W_in); scan overwrites emb[t] with h_t
// after consuming u_t = proj[t] (same thread -> no hazard).
// d_ws: 256 flags at 64B stride (16 KB), memset 0 on stream.
// ============================================================================

#define T_STEPS 1024
#define HDIM    1024
#define EUL     0.01f
#define FPAD    16   // u32s per flag line (64B)

typedef unsigned long long u64_t;

// Coherent (L1+L2-bypassing) 16B load as 2x 8B system-scope relaxed atomics.
__device__ __forceinline__ float4 ldg_sys16(const float* p) {
  union { u64_t u; float f[2]; } a, b;
  a.u = __hip_atomic_load((const u64_t*)p,       __ATOMIC_RELAXED,
                          __HIP_MEMORY_SCOPE_SYSTEM);
  b.u = __hip_atomic_load((const u64_t*)(p + 2), __ATOMIC_RELAXED,
                          __HIP_MEMORY_SCOPE_SYSTEM);
  float4 r;
  r.x = a.f[0]; r.y = a.f[1]; r.z = b.f[0]; r.w = b.f[1];
  return r;
}

__device__ __forceinline__ void fma4(float4& a, float s, const float4& v) {
  a.x += s * v.x; a.y += s * v.y; a.z += s * v.z; a.w += s * v.w;
}

// ---------------------------------------------------------------------------
// Generic fp32 GEMM: C[M,N] = A[M,K] @ B[K,N], row-major, M%64==N%64==K%16==0
// 64x64 tile, 256 threads, 4x4 microtile.  (unchanged)
// ---------------------------------------------------------------------------
__global__ __launch_bounds__(256) void gemm_f32(const float* __restrict__ A,
                                                const float* __restrict__ B,
                                                float* __restrict__ C,
                                                int M, int N, int K) {
  __shared__ float As[16][68];
  __shared__ float Bs[16][68];
  const int tid = threadIdx.x;
  const int tx = tid & 15;
  const int ty = tid >> 4;
  const int m0 = blockIdx.y * 64;
  const int n0 = blockIdx.x * 64;
  float acc[4][4] = {};

  for (int k0 = 0; k0 < K; k0 += 16) {
    {
      const int m = tid >> 2;
      const int k = (tid & 3) * 4;
      const float4 a = *(const float4*)(A + (long)(m0 + m) * K + k0 + k);
      As[k + 0][m] = a.x; As[k + 1][m] = a.y;
      As[k + 2][m] = a.z; As[k + 3][m] = a.w;
      const int kb = tid >> 4;
      const int n  = (tid & 15) * 4;
      *(float4*)&Bs[kb][n] = *(const float4*)(B + (long)(k0 + kb) * N + n0 + n);
    }
    __syncthreads();
#pragma unroll
    for (int k = 0; k < 16; ++k) {
      const float4 a = *(const float4*)&As[k][ty * 4];
      const float4 b = *(const float4*)&Bs[k][tx * 4];
      acc[0][0] += a.x * b.x; acc[0][1] += a.x * b.y; acc[0][2] += a.x * b.z; acc[0][3] += a.x * b.w;
      acc[1][0] += a.y * b.x; acc[1][1] += a.y * b.y; acc[1][2] += a.y * b.z; acc[1][3] += a.y * b.w;
      acc[2][0] += a.z * b.x; acc[2][1] += a.z * b.y; acc[2][2] += a.z * b.z; acc[2][3] += a.z * b.w;
      acc[3][0] += a.w * b.x; acc[3][1] += a.w * b.y; acc[3][2] += a.w * b.z; acc[3][3] += a.w * b.w;
    }
    __syncthreads();
  }
#pragma unroll
  for (int i = 0; i < 4; ++i) {
    float4 o;
    o.x = acc[i][0]; o.y = acc[i][1]; o.z = acc[i][2]; o.w = acc[i][3];
    *(float4*)(C + (long)(m0 + ty * 4 + i) * N + n0 + tx * 4) = o;
  }
}

// ---------------------------------------------------------------------------
// Persistent scan kernel, 512 threads.
// Grid: 256 WGs = 8 batch-groups (g = w&7, rows 8g..8g+8) x 32 col slices
// (c = w>>3, cols 32c..32c+32).
// Thread: qd = tid>>6 (wave, j-quad: cols cb+4qd..+4; also staging row qd),
//         l  = tid&63 (i-split: phase-p rows p*512 + 8l .. +8;
//                      staging cols ph0 [8l,8l+8), ph1 [512+8l, +8)).
// Weights: Creg[p*8+r] = (B+C)[p*512+8l+r][cb+4qd..+4] in VGPRs (64 regs).
// LDS: hls[2][8][512] staged prev h, swizzled by perm(slot)=slot^((slot>>3)&7)
//      at 16B-slot granularity; conflict-free to the wave64-b128 minimum.
// Reduce: shfl_xor reduce-scatter; lane ends with output (b_f,j_f),
//         b_f=(l&31)>>2, j_f=4qd+(l&3); lanes 0..31 store.
// Publish: per-wave vmcnt(0), __syncthreads, tid0 stores flags[w*16]=t+1
// (plain relaxed system store; flag = steps published; 1 line per flag).
// ---------------------------------------------------------------------------
__global__ __launch_bounds__(512, 2) void scan_kernel(
    const float* __restrict__ block_mat,
    const float* __restrict__ coupling_mat,
    float* __restrict__ emb,          // [T][64][1024]; holds proj on entry
    unsigned int* __restrict__ flags) // [256*FPAD], zeroed before launch
{
  __shared__ float hls[2][8 * 512];   // 32 KB staged h (2 phase buffers)
  __shared__ float lds_pad[16384];    // 64 KB pad: total 96KB -> 1 WG/CU

  const int tid = threadIdx.x;
  // volatile so the pad cannot be dead-store-eliminated
  *(volatile float*)&lds_pad[tid] = 0.f;

  const int w = blockIdx.x;
  const int g = w & 7;            // batch group -> rows [8g, 8g+8)
  const int c = w >> 3;           // col slice   -> cols [32c, 32c+32)
  const int b0 = g * 8;
  const int cb = c * 32;
  const int bk = c >> 1;          // 64-wide diag block index (WG-uniform)
  const int blk_phase = bk >> 3;  // phase containing own-block rows
  const int qd = tid >> 6;        // wave id = j-quad = staging row
  const int l  = tid & 63;        // lane = i-split = staging col chunk
  const int lf = l & 31;
  const int b_f = lf >> 2;                // output batch row 0..7
  const int j_f = (qd << 2) | (lf & 3);   // output col within slice

  // in-block: thread's chunk rows (phase-local 8l..8l+8) inside diag block?
  const bool in_blk = ((l >> 3) == (bk & 7));
  const float km = in_blk ? 0.f : 1.f;    // fmaxf(h, h*km): relu iff in_blk

  // swizzled 16B-slot indices (same for staging write and compute read)
  const int s0 = 2 * l, s1 = 2 * l + 1;
  const int rs0 = s0 ^ ((s0 >> 3) & 7);
  const int rs1 = s1 ^ ((s1 >> 3) & 7);

  // h_old address (own previous-state element)
  const int gcol = cb + j_f;
  const int hop = gcol >> 9;              // phase buf holding own col
  const int il = gcol & 511;
  const int hslot = il >> 2;
  const int hperm = hslot ^ ((hslot >> 3) & 7);
  const int hoff = b_f * 512 + (hperm << 2) + (il & 3);

  // ---- fused weight slice into registers: 16 rows x 4 cols (64 VGPRs)
  float4 Creg[16];
#pragma unroll
  for (int p = 0; p < 2; ++p) {
#pragma unroll
    for (int r = 0; r < 8; ++r) {
      const long i = (long)(p * 512 + l * 8 + r);
      const float4 bv = *(const float4*)(block_mat    + i * HDIM + cb + (qd << 2));
      const float4 cv = *(const float4*)(coupling_mat + i * HDIM + cb + (qd << 2));
      float4 rr;
      rr.x = bv.x + cv.x; rr.y = bv.y + cv.y;
      rr.z = bv.z + cv.z; rr.w = bv.w + cv.w;
      Creg[p * 8 + r] = rr;
    }
  }

  // flags this thread polls (producers of its staged col chunks), padded idx
  const int f0 = (((l >> 2) << 3) | g) * FPAD;   // phase-0 producer
  const int f1 = f0 + 128 * FPAD;                // phase-1 producer

  long spin_budget = 20000000;  // lifetime poll budget: hang-safety valve

// one phase of the dense matvec: 16 ds_read_b128 + 64 fma4 (+ relu select)
#define PHASE_MAC(P)                                                        \
  {                                                                         \
    const bool do_relu = ((P) == blk_phase);                                \
    _Pragma("unroll")                                                       \
    for (int b = 0; b < 8; ++b) {                                           \
      const float* Hb = &hls[(P)][b * 512];                                 \
      float4 h0 = *(const float4*)(Hb + (rs0 << 2));                        \
      float4 h1 = *(const float4*)(Hb + (rs1 << 2));                        \
      if (do_relu) {                                                        \
        h0.x = fmaxf(h0.x, h0.x * km); h0.y = fmaxf(h0.y, h0.y * km);       \
        h0.z = fmaxf(h0.z, h0.z * km); h0.w = fmaxf(h0.w, h0.w * km);       \
        h1.x = fmaxf(h1.x, h1.x * km); h1.y = fmaxf(h1.y, h1.y * km);       \
        h1.z = fmaxf(h1.z, h1.z * km); h1.w = fmaxf(h1.w, h1.w * km);       \
      }                                                                     \
      fma4(acc[b], h0.x, Creg[(P) * 8 + 0]);                                \
      fma4(acc[b], h0.y, Creg[(P) * 8 + 1]);                                \
      fma4(acc[b], h0.z, Creg[(P) * 8 + 2]);                                \
      fma4(acc[b], h0.w, Creg[(P) * 8 + 3]);                                \
      fma4(acc[b], h1.x, Creg[(P) * 8 + 4]);                                \
      fma4(acc[b], h1.y, Creg[(P) * 8 + 5]);                                \
      fma4(acc[b], h1.z, Creg[(P) * 8 + 6]);                                \
      fma4(acc[b], h1.w, Creg[(P) * 8 + 7]);                                \
    }                                                                       \
  }

  for (int t = 0; t < T_STEPS; ++t) {
    float4 acc[8];
#pragma unroll
    for (int b = 0; b < 8; ++b) { acc[b].x = 0.f; acc[b].y = 0.f; acc[b].z = 0.f; acc[b].w = 0.f; }
    float h_old = 0.f;

    // u_t = proj[t] for our output element; only lanes 0..31 produce output
    float u = 0.f;
    if (l < 32) u = emb[((long)t * 64 + b0 + b_f) * HDIM + cb + j_f];

    if (t > 0) {
      const unsigned int tgt = (unsigned int)t;  // flag = steps published

      // ---- single merged poll: both producers in one loop (R2-proven)
      while (true) {
        const unsigned int a = __hip_atomic_load(&flags[f0], __ATOMIC_RELAXED,
                                                 __HIP_MEMORY_SCOPE_SYSTEM);
        const unsigned int b = __hip_atomic_load(&flags[f1], __ATOMIC_RELAXED,
                                                 __HIP_MEMORY_SCOPE_SYSTEM);
        if (a >= tgt && b >= tgt) break;
        __builtin_amdgcn_s_sleep(4);
        if (--spin_budget < 0) break;
      }
      asm volatile("" ::: "memory");  // keep data loads after the poll

      // ---- issue ALL staged loads up-front (both phases)
      const float* src0 =
          emb + ((long)(t - 1) * 64 + b0 + qd) * HDIM + (l << 3);
      const float4 stg0a = ldg_sys16(src0);
      const float4 stg0b = ldg_sys16(src0 + 4);
      const float4 stg1a = ldg_sys16(src0 + 512);
      const float4 stg1b = ldg_sys16(src0 + 516);

      // ---- write phase 0 (row qd, swizzled slots 2l, 2l+1)
      *(float4*)&hls[0][qd * 512 + (rs0 << 2)] = stg0a;
      *(float4*)&hls[0][qd * 512 + (rs1 << 2)] = stg0b;
      __syncthreads();  // bar_a: phase-0 staged & visible

      if (hop == 0) h_old = hls[0][hoff];  // safe: hls[0] stable until bar_b
      PHASE_MAC(0)

      // ---- write phase 1 (disjoint buffer; latency hidden under MAC0)
      *(float4*)&hls[1][qd * 512 + (rs0 << 2)] = stg1a;
      *(float4*)&hls[1][qd * 512 + (rs1 << 2)] = stg1b;
      __syncthreads();  // bar_b: phase-1 staged; also gates next-step write0

      if (hop == 1) h_old = hls[1][hoff];  // safe until end-of-step barrier
      PHASE_MAC(1)
    }

    // ---- reduce-scatter 64-way i-split over the wave (shfl only).
    float red[32];
#pragma unroll
    for (int b = 0; b < 8; ++b) {
      red[b * 4 + 0] = acc[b].x;
      red[b * 4 + 1] = acc[b].y;
      red[b * 4 + 2] = acc[b].z;
      red[b * 4 + 3] = acc[b].w;
    }
#define RED_ROUND(M)                                              \
    {                                                             \
      const bool hi = (l & (M)) != 0;                             \
      _Pragma("unroll")                                           \
      for (int q = 0; q < (M); ++q) {                             \
        const float lo = red[q], hv2 = red[q + (M)];              \
        const float keep = hi ? hv2 : lo;                         \
        const float give = hi ? lo : hv2;                         \
        red[q] = keep + __shfl_xor(give, (M), 64);                \
      }                                                           \
    }
    RED_ROUND(16)
    RED_ROUND(8)
    RED_ROUND(4)
    RED_ROUND(2)
    RED_ROUND(1)
#undef RED_ROUND
    const float tot = red[0] + __shfl_xor(red[0], 32, 64);

    // ---- Euler update + publish (store bypasses L1/L2 -> visible at LLC)
    const float hn = h_old + EUL * (-h_old + tot + u);
    if (l < 32) {  // lanes 0..31 hold the canonical copy
      __hip_atomic_store(&emb[((long)t * 64 + b0 + b_f) * HDIM + cb + j_f], hn,
                         __ATOMIC_RELAXED, __HIP_MEMORY_SCOPE_SYSTEM);
    }
    // per-wave drain, then WG barrier, then ONE plain flag store (no RMW)
    asm volatile("s_waitcnt vmcnt(0)" ::: "memory");
    __syncthreads();  // all 8 waves' h-stores are complete at LLC here
    if (tid == 0) {
      __hip_atomic_store(&flags[w * FPAD], (unsigned int)(t + 1),
                         __ATOMIC_RELAXED, __HIP_MEMORY_SCOPE_SYSTEM);
    }
  }
#undef PHASE_MAC
}

// ---------------------------------------------------------------------------
extern "C" void kernel_launch(void* const* d_in, const int* in_sizes, int n_in,
                              void* d_out, int out_size, void* d_ws,
                              size_t ws_size, hipStream_t stream) {
  (void)in_sizes; (void)n_in; (void)out_size; (void)ws_size;
  const float* input     = (const float*)d_in[0];  // [1024*64, 256]
  const float* input_mat = (const float*)d_in[1];  // [256, 1024]
  const float* block_mat = (const float*)d_in[2];  // [1024, 1024]
  const float* coupling  = (const float*)d_in[3];  // [1024, 1024]
  const float* out_mat   = (const float*)d_in[4];  // [1024, 256]

  float* out_ptr = (float*)d_out;                       // [65536, 256]
  float* emb_ptr = out_ptr + (size_t)1024 * 64 * 256;   // [65536, 1024]
  unsigned int* flags = (unsigned int*)d_ws;

  // 1) proj = input @ input_mat  -> embeddings region (consumed in-place)
  gemm_f32<<<dim3(1024 / 64, 65536 / 64), 256, 0, stream>>>(
      input, input_mat, emb_ptr, 65536, 1024, 256);

  // 2) zero the padded step flags (256 flags x 64B lines = 16 KB)
  hipMemsetAsync(flags, 0, 256 * FPAD * sizeof(unsigned int), stream);

  // 3) persistent scan (256 WGs x 512 threads, 1/CU by LDS footprint)
  scan_kernel<<<256, 512, 0, stream>>>(block_mat, coupling, emb_ptr, flags);

  // 4) output = embeddings @ out_mat
  gemm_f32<<<dim3(256 / 64, 65536 / 64), 256, 0, stream>>>(
      emb_ptr, out_mat, out_ptr, 65536, 256, 1024);
}